// Round 7
// baseline (188.577 us; speedup 1.0000x reference)
//
#include <hip/hip_runtime.h>
#include <math.h>

#define IMG_W 3840
#define IMG_H 2160
#define OUTW  120       // output cols per wave (32 strips exact: 32*120 = 3840)
#define R     20        // output rows per strip (2160 = 108 * 20)
#define ITERS (R + 4)   // gray rows loaded per strip

// idx -> dx [1,1,0,-1,-1,-1,0,1], dy [0,1,1,1,0,-1,-1,-1], packed as (d+1) 2-bit fields
#define DXPACK 0x901A
#define DYPACK 0x1A9
// Sector boundary slopes in scaled-degree space (RAD2DEG = 180/3.14159)
#define T1_SLOPE 0.41421317376456f
#define T2_SLOPE 2.41420676743300f
#define SECT_EPS 3.0e-5f
#define FIX_CAP  (1u << 22)

__device__ __noinline__ int slow_sector(float sx, float sy) {
#pragma clang fp contract(off)
    const float RADF = (float)(180.0 / 3.14159);
    float t = atan2f(sy, sx);
    float wv = ((t * RADF) + 180.0f) / 45.0f;   // exact f32 chain as reference
    float ori = rintf(wv);                      // round-half-even == np.round
    float fr = fabsf(wv - ori);
    if (fr > 0.4995f) {
        double td = atan2((double)sy, (double)sx);
        float t2 = (float)td;
        wv = ((t2 * RADF) + 180.0f) / 45.0f;
        ori = rintf(wv);
    }
    return ((int)ori) & 7;
}

__global__ void zero_counter(unsigned* fix) { if (threadIdx.x == 0) fix[0] = 0u; }

// ---------------- main kernel: call-free, branchless loads, float2/lane ----------------
__global__ __launch_bounds__(256, 3) void canny_main(const float* __restrict__ img,
                                                     float* __restrict__ out,
                                                     unsigned* __restrict__ fix) {
#pragma clang fp contract(off)
    __shared__ float ring[4 * 512];              // [wave][slot 0..3][col 0..127], 8 KB

    const int lane = threadIdx.x;                // 0..63
    const int wv   = threadIdx.y;                // 0..3
    float* rbase = ring + wv * 512;

    const int strip = blockIdx.x * 4 + wv;       // 0..31
    const int X0 = strip * OUTW;
    const int Y0 = blockIdx.y * R;
    const int r0 = 2 * lane;                     // rel gray cols r0, r0+1
    const int x0 = X0 - 2 + r0;
    const int x1 = x0 + 1;
    const bool xk0 = (unsigned)x0 < (unsigned)IMG_W;
    const bool xk1 = (unsigned)x1 < (unsigned)IMG_W;
    const bool outok = (lane >= 1) && (lane <= 60);      // out cols X0..X0+119
    const int  rb = outok ? r0 : 2;              // safe LDS index for masked lanes
    const int  xc = min(max(x0, 0), IMG_W - 2);  // even -> 8B-aligned float2 loads

    const float* p0 = img + xc;
    const float* p1 = p0 + (size_t)IMG_W * IMG_H;
    const float* p2 = p1 + (size_t)IMG_W * IMG_H;

    float GL[3], G0[3], G1[3], GR[3];            // rolling gray rows (4 cols each)
    float mc0 = 0.f, mc1 = 0.f;                  // lag-1 center mags
    int dx0 = 0, dy0 = 0, dx1 = 0, dy1 = 0;      // lag-1 sectors

#pragma unroll
    for (int k = 0; k < ITERS; ++k) {
        // ---- unconditional clamped load of gray row y = Y0-2+k ----
        const int y = Y0 - 2 + k;
        const bool yok = (unsigned)y < (unsigned)IMG_H;
        const int yc = min(max(y, 0), IMG_H - 1);
        const size_t o = (size_t)yc * IMG_W;
        const float2 A = *(const float2*)(p0 + o);
        const float2 B = *(const float2*)(p1 + o);
        const float2 C = *(const float2*)(p2 + o);
        float t0 = ((A.x + B.x) + C.x) / 3.0f;   // left-assoc, true div (match ref)
        float t1 = ((A.y + B.y) + C.y) / 3.0f;
        const int s = k % 3;
        float g0 = (yok && xk0) ? t0 : 0.0f;
        float g1 = (yok && xk1) ? t1 : 0.0f;
        G0[s] = g0;
        G1[s] = g1;
        GL[s] = __shfl_up(g1, 1);                // col r0-1 (lane l-1's g1)
        GR[s] = __shfl_down(g0, 1);              // col r0+2 (lane l+1's g0)

        if (k >= 2) {
            const int i0 = (k - 2) % 3, i1 = (k - 1) % 3, i2 = k % 3;
            const int m = y - 1;                 // mag row
            const bool mok = (unsigned)m < (unsigned)IMG_H;

            // px0 (col r0): taps (GL,G0,G1); exact R6 op order
            float sx0 = GL[i0];
            sx0 = sx0 - G1[i0];
            sx0 = sx0 + 2.0f * GL[i1];
            sx0 = sx0 - 2.0f * G1[i1];
            sx0 = sx0 + GL[i2];
            sx0 = sx0 - G1[i2];
            float sy0 = GL[i0];
            sy0 = sy0 + 2.0f * G0[i0];
            sy0 = sy0 + G1[i0];
            sy0 = sy0 - GL[i2];
            sy0 = sy0 - 2.0f * G0[i2];
            sy0 = sy0 - G1[i2];
            float mag0 = sqrtf(sx0 * sx0 + sy0 * sy0);

            // px1 (col r0+1): taps (G0,G1,GR)
            float sx1 = G0[i0];
            sx1 = sx1 - GR[i0];
            sx1 = sx1 + 2.0f * G0[i1];
            sx1 = sx1 - 2.0f * GR[i1];
            sx1 = sx1 + G0[i2];
            sx1 = sx1 - GR[i2];
            float sy1 = G0[i0];
            sy1 = sy1 + 2.0f * G1[i0];
            sy1 = sy1 + GR[i0];
            sy1 = sy1 - G0[i2];
            sy1 = sy1 - 2.0f * G1[i2];
            sy1 = sy1 - GR[i2];
            float mag1 = sqrtf(sx1 * sx1 + sy1 * sy1);

            // grad_mag exists only on HxW (dir-conv zero-pads): mask OOB centers
            float M0 = (mok && xk0) ? mag0 : 0.0f;
            float M1 = (mok && xk1) ? mag1 : 0.0f;

            // fast sector -> (dx,dy); eps-band pixels deferred to fixup kernel
            float ax0 = fabsf(sx0), ay0 = fabsf(sy0);
            float d10 = fmaf(-T1_SLOPE, ax0, ay0);
            float d20 = fmaf(-T2_SLOPE, ax0, ay0);
            float sA0 = ax0 + ay0;
            int ndx0 = (d20 > 0.0f) ? 0 : ((sx0 > 0.0f) ? -1 : 1);
            int ndy0 = (d10 < 0.0f) ? 0 : ((sy0 > 0.0f) ? -1 : 1);
            bool inb0 = (fabsf(d10) < SECT_EPS * sA0) || (fabsf(d20) < SECT_EPS * sA0);

            float ax1 = fabsf(sx1), ay1 = fabsf(sy1);
            float d11 = fmaf(-T1_SLOPE, ax1, ay1);
            float d21 = fmaf(-T2_SLOPE, ax1, ay1);
            float sA1 = ax1 + ay1;
            int ndx1 = (d21 > 0.0f) ? 0 : ((sx1 > 0.0f) ? -1 : 1);
            int ndy1 = (d11 < 0.0f) ? 0 : ((sy1 > 0.0f) ? -1 : 1);
            bool inb1 = (fabsf(d11) < SECT_EPS * sA1) || (fabsf(d21) < SECT_EPS * sA1);

            // defer ambiguous-sector output pixels (~1e-4 of pixels); if mag<0.2
            // the output is 0 for any sector, so no flag needed
            bool f0 = inb0 && outok && (M0 >= 0.2f);
            bool f1 = inb1 && outok && (M1 >= 0.2f);
            if (f0 || f1) {
                if (f0) {
                    unsigned id = atomicAdd(fix, 1u);
                    if (id < FIX_CAP) fix[1 + id] = ((unsigned)m << 12) | (unsigned)x0;
                }
                if (f1) {
                    unsigned id = atomicAdd(fix, 1u);
                    if (id < FIX_CAP) fix[1 + id] = ((unsigned)m << 12) | (unsigned)x1;
                }
            }

            // ring write (slot (k-2)&3); same-wave DS ops are in-order -> no barrier
            float* wr = rbase + ((k - 2) & 3) * 128;
            *(float2*)(wr + r0) = make_float2(M0, M1);

            // ---- NMS for row n = m-1 (rows n-1,n,n+1 all resident in ring) ----
            if (k >= 4) {
                const int n = m - 1;             // = Y0 + k - 4
                float* bA = rbase + ((k - 4) & 3) * 128;  // row n-1
                float* bB = rbase + ((k - 3) & 3) * 128;  // row n
                float* bC = rbase + ((k - 2) & 3) * 128;  // row n+1
                float* bp0 = (dy0 < 0) ? bA : ((dy0 > 0) ? bC : bB);
                float* bn0 = (dy0 < 0) ? bC : ((dy0 > 0) ? bA : bB);
                float* bp1 = (dy1 < 0) ? bA : ((dy1 > 0) ? bC : bB);
                float* bn1 = (dy1 < 0) ? bC : ((dy1 > 0) ? bA : bB);
                float mp0 = bp0[rb + dx0];
                float mn0 = bn0[rb - dx0];
                float mp1 = bp1[rb + 1 + dx1];
                float mn1 = bn1[rb + 1 - dx1];
                float r0v = (fminf(mc0 - mp0, mc0 - mn0) > 0.0f && mc0 >= 0.2f) ? 1.0f : 0.0f;
                float r1v = (fminf(mc1 - mp1, mc1 - mn1) > 0.0f && mc1 >= 0.2f) ? 1.0f : 0.0f;
                if (outok)
                    *(float2*)(out + (size_t)n * IMG_W + x0) = make_float2(r0v, r1v);
            }
            mc0 = M0; mc1 = M1;
            dx0 = ndx0; dy0 = ndy0; dx1 = ndx1; dy1 = ndy1;
        }
    }
}

// ---------------- fixup kernel: exact recompute of deferred pixels ----------------
__device__ __forceinline__ float gray_at(const float* img, int xx, int yy) {
#pragma clang fp contract(off)
    if ((unsigned)xx >= (unsigned)IMG_W || (unsigned)yy >= (unsigned)IMG_H) return 0.0f;
    size_t o = (size_t)yy * IMG_W + xx;
    float c0 = img[o];
    float c1 = img[o + (size_t)IMG_W * IMG_H];
    float c2 = img[o + 2 * (size_t)IMG_W * IMG_H];
    return ((c0 + c1) + c2) / 3.0f;
}

__device__ void sobel_at(const float* img, int xx, int yy, float& sxo, float& syo) {
#pragma clang fp contract(off)
    float a00 = gray_at(img, xx - 1, yy - 1), a01 = gray_at(img, xx, yy - 1), a02 = gray_at(img, xx + 1, yy - 1);
    float a10 = gray_at(img, xx - 1, yy),                                     a12 = gray_at(img, xx + 1, yy);
    float a20 = gray_at(img, xx - 1, yy + 1), a21 = gray_at(img, xx, yy + 1), a22 = gray_at(img, xx + 1, yy + 1);
    float s = a00;
    s = s - a02;
    s = s + 2.0f * a10;
    s = s - 2.0f * a12;
    s = s + a20;
    s = s - a22;
    sxo = s;
    float t = a00;
    t = t + 2.0f * a01;
    t = t + a02;
    t = t - a20;
    t = t - 2.0f * a21;
    t = t - a22;
    syo = t;
}

__device__ float mag_at(const float* img, int xx, int yy) {
#pragma clang fp contract(off)
    if ((unsigned)xx >= (unsigned)IMG_W || (unsigned)yy >= (unsigned)IMG_H) return 0.0f;
    float sx, sy;
    sobel_at(img, xx, yy, sx, sy);
    return sqrtf(sx * sx + sy * sy);
}

__global__ void canny_fixup(const float* __restrict__ img, float* __restrict__ out,
                            const unsigned* __restrict__ fix) {
#pragma clang fp contract(off)
    unsigned cnt = fix[0];
    if (cnt > FIX_CAP) cnt = FIX_CAP;
    for (unsigned i = blockIdx.x * blockDim.x + threadIdx.x; i < cnt;
         i += gridDim.x * blockDim.x) {
        unsigned pk = fix[1 + i];
        int xx = (int)(pk & 4095u), yy = (int)(pk >> 12);
        float sx, sy;
        sobel_at(img, xx, yy, sx, sy);
        int idx = slow_sector(sx, sy);           // exact atan2 (+double rescue) path
        int dxo = ((DXPACK >> (2 * idx)) & 3) - 1;
        int dyo = ((DYPACK >> (2 * idx)) & 3) - 1;
        float mc = sqrtf(sx * sx + sy * sy);
        float mp = mag_at(img, xx + dxo, yy + dyo);
        float mn = mag_at(img, xx - dxo, yy - dyo);
        out[(size_t)yy * IMG_W + xx] =
            (fminf(mc - mp, mc - mn) > 0.0f && mc >= 0.2f) ? 1.0f : 0.0f;
    }
}

extern "C" void kernel_launch(void* const* d_in, const int* in_sizes, int n_in,
                              void* d_out, int out_size, void* d_ws, size_t ws_size,
                              hipStream_t stream) {
    const float* img = (const float*)d_in[0];
    float* out = (float*)d_out;
    unsigned* fix = (unsigned*)d_ws;             // [0]=count, [1..]=packed (y<<12|x)
    zero_counter<<<1, 64, 0, stream>>>(fix);
    canny_main<<<dim3(8, IMG_H / R), dim3(64, 4), 0, stream>>>(img, out, fix);
    canny_fixup<<<dim3(16), dim3(256), 0, stream>>>(img, out, fix);
}